// Round 5
// baseline (352.245 us; speedup 1.0000x reference)
//
#include <hip/hip_runtime.h>
#include <hip/hip_bf16.h>

#define NNODES 100000
#define NEDGES 1600000
#define DIN 128
#define DOUT 128
#define NHEADS 4
#define NEG_SLOPE 0.2f
#define LN_EPS 1e-5f

typedef __attribute__((ext_vector_type(8))) short bf16x8;
typedef __attribute__((ext_vector_type(4))) float f32x4;

__device__ inline ushort f2b(float f) {
  union { float f; uint u; } v; v.f = f;
  uint r = v.u + 0x7fff + ((v.u >> 16) & 1);   // RNE
  return (ushort)(r >> 16);
}

#define NBH ((NEDGES + 255) / 256)   // 6250 hist blocks

// ---------------- hist (+int rank) fused with W transpose+cast ----------------
__global__ __launch_bounds__(256) void k_hist_wt(
    const int* __restrict__ ei, int* __restrict__ deg, int* __restrict__ rank,
    const float* __restrict__ W, ushort* __restrict__ Wt) {
  if (blockIdx.x == NBH) {
    int t = threadIdx.x;
    int n = t >> 1;
    int kb = (t & 1) * 64;
    for (int i = 0; i < 16; ++i) {
      ushort4 p;
      p.x = f2b(W[(kb + 4 * i + 0) * DOUT + n]);
      p.y = f2b(W[(kb + 4 * i + 1) * DOUT + n]);
      p.z = f2b(W[(kb + 4 * i + 2) * DOUT + n]);
      p.w = f2b(W[(kb + 4 * i + 3) * DOUT + n]);
      *(ushort4*)&Wt[n * DIN + kb + 4 * i] = p;
    }
    return;
  }
  int e = blockIdx.x * 256 + threadIdx.x;
  if (e < NEDGES) rank[e] = atomicAdd(&deg[ei[NEDGES + e]], 1);
}

// ---------------- MFMA GEMM: direct-from-global A frags, W^T-only LDS ----------------
#define BM 128
#define LDP 136

__global__ __launch_bounds__(256) void k_gemm(
    const float* __restrict__ x, const ushort* __restrict__ Wt,
    const float* __restrict__ att_src, const float* __restrict__ att_dst,
    ushort* __restrict__ h, float* __restrict__ a_src, float* __restrict__ a_dst) {
  __shared__ __align__(16) ushort Ws[DOUT][LDP];
  const int t = threadIdx.x;
  const int brow = blockIdx.x * BM;
  {
    const int row = t >> 1, cb = (t & 1) * 64;
    const ushort* srcp = &Wt[row * DIN + cb];
#pragma unroll
    for (int i = 0; i < 8; ++i)
      *(bf16x8*)&Ws[row][cb + 8 * i] = *(const bf16x8*)(srcp + 8 * i);
  }
  __syncthreads();

  const int w = t >> 6, l = t & 63;
  const int lr = l & 15, lg = l >> 4;
  const int r0 = brow + w * 32 + lr;
  const int r1 = r0 + 16;
  const float* x0 = &x[(size_t)min(r0, NNODES - 1) * DIN + lg * 8];
  const float* x1 = &x[(size_t)min(r1, NNODES - 1) * DIN + lg * 8];

  float4 xf[2][4][2];
#pragma unroll
  for (int k0 = 0; k0 < 4; ++k0) {
    xf[0][k0][0] = *(const float4*)(x0 + k0 * 32);
    xf[0][k0][1] = *(const float4*)(x0 + k0 * 32 + 4);
    xf[1][k0][0] = *(const float4*)(x1 + k0 * 32);
    xf[1][k0][1] = *(const float4*)(x1 + k0 * 32 + 4);
  }
  bf16x8 afr[2][4];
#pragma unroll
  for (int mi = 0; mi < 2; ++mi)
#pragma unroll
    for (int k0 = 0; k0 < 4; ++k0) {
      float4 a = xf[mi][k0][0], b = xf[mi][k0][1];
      bf16x8 v;
      v[0] = (short)f2b(a.x); v[1] = (short)f2b(a.y);
      v[2] = (short)f2b(a.z); v[3] = (short)f2b(a.w);
      v[4] = (short)f2b(b.x); v[5] = (short)f2b(b.y);
      v[6] = (short)f2b(b.z); v[7] = (short)f2b(b.w);
      afr[mi][k0] = v;
    }

  f32x4 acc[2][8];
#pragma unroll
  for (int mi = 0; mi < 2; ++mi)
#pragma unroll
    for (int ni = 0; ni < 8; ++ni)
      acc[mi][ni] = (f32x4){0.f, 0.f, 0.f, 0.f};

#pragma unroll
  for (int k0 = 0; k0 < 4; ++k0) {
#pragma unroll
    for (int ni = 0; ni < 8; ++ni) {
      bf16x8 b = *(const bf16x8*)&Ws[ni * 16 + lr][k0 * 32 + lg * 8];
      acc[0][ni] = __builtin_amdgcn_mfma_f32_16x16x32_bf16(afr[0][k0], b, acc[0][ni], 0, 0, 0);
      acc[1][ni] = __builtin_amdgcn_mfma_f32_16x16x32_bf16(afr[1][k0], b, acc[1][ni], 0, 0, 0);
    }
  }

  float asr[8], adr[8];
#pragma unroll
  for (int ni = 0; ni < 8; ++ni) {
    asr[ni] = att_src[ni * 16 + lr];
    adr[ni] = att_dst[ni * 16 + lr];
  }

#pragma unroll
  for (int mi = 0; mi < 2; ++mi) {
#pragma unroll
    for (int r = 0; r < 4; ++r) {
      const int row = brow + w * 32 + mi * 16 + lg * 4 + r;
      float ps[NHEADS] = {0.f, 0.f, 0.f, 0.f};
      float pd[NHEADS] = {0.f, 0.f, 0.f, 0.f};
#pragma unroll
      for (int ni = 0; ni < 8; ++ni) {
        float v = acc[mi][ni][r];
        ps[ni >> 1] += v * asr[ni];
        pd[ni >> 1] += v * adr[ni];
        if (row < NNODES) h[(size_t)row * DOUT + ni * 16 + lr] = f2b(v);
      }
#pragma unroll
      for (int off = 1; off < 16; off <<= 1) {
#pragma unroll
        for (int hh = 0; hh < NHEADS; ++hh) {
          ps[hh] += __shfl_xor(ps[hh], off);
          pd[hh] += __shfl_xor(pd[hh], off);
        }
      }
      if (lr == 0 && row < NNODES) {
        *(float4*)&a_src[row * NHEADS] = make_float4(ps[0], ps[1], ps[2], ps[3]);
        *(float4*)&a_dst[row * NHEADS] = make_float4(pd[0], pd[1], pd[2], pd[3]);
      }
    }
  }
}

// ---------------- CSR offsets (scan) ----------------
__global__ __launch_bounds__(256) void k_blocksum(const int* __restrict__ deg,
                                                  int* __restrict__ bsum) {
  int i = blockIdx.x * 256 + threadIdx.x;
  int v = (i < NNODES) ? deg[i] : 0;
  for (int off = 1; off < 64; off <<= 1) v += __shfl_xor(v, off);
  __shared__ int s[4];
  if ((threadIdx.x & 63) == 0) s[threadIdx.x >> 6] = v;
  __syncthreads();
  if (threadIdx.x == 0) bsum[blockIdx.x] = s[0] + s[1] + s[2] + s[3];
}

__global__ __launch_bounds__(512) void k_scanbsum(int* __restrict__ bsum, int nb,
                                                  int* __restrict__ offsets) {
  __shared__ int s[512];
  int t = threadIdx.x;
  int v = (t < nb) ? bsum[t] : 0;
  s[t] = v;
  __syncthreads();
  for (int off = 1; off < 512; off <<= 1) {
    int a = 0;
    if (t >= off) a = s[t - off];
    __syncthreads();
    s[t] += a;
    __syncthreads();
  }
  int excl = (t == 0) ? 0 : s[t - 1];
  if (t < nb) bsum[t] = excl;
  if (t == 0) offsets[NNODES] = NEDGES;
}

__global__ __launch_bounds__(256) void k_offsets(const int* __restrict__ deg,
                                                 const int* __restrict__ bsum,
                                                 int* __restrict__ offsets) {
  __shared__ int s[256];
  int t = threadIdx.x;
  int i = blockIdx.x * 256 + t;
  int d = (i < NNODES) ? deg[i] : 0;
  s[t] = d;
  __syncthreads();
  for (int off = 1; off < 256; off <<= 1) {
    int a = 0;
    if (t >= off) a = s[t - off];
    __syncthreads();
    s[t] += a;
    __syncthreads();
  }
  int excl = s[t] - d + bsum[blockIdx.x];
  if (i < NNODES) offsets[i] = excl;
}

__global__ void k_scatter(const int* __restrict__ ei, const int* __restrict__ rank,
                          const int* __restrict__ offs, int* __restrict__ ssrc) {
  int e = blockIdx.x * blockDim.x + threadIdx.x;
  if (e < NEDGES) {
    int dst = ei[NEDGES + e];
    ssrc[offs[dst] + rank[e]] = ei[e];
  }
}

// ---------------- fused aggregate + bias + LN + PReLU + residual ----------------
// One 64-lane wave per node; lane l owns channels 2l,2l+1 (head = l>>4).
// Hand-unrolled x8 (named scalars only -> no scratch). No segment-max (|e|<~8).
__global__ __launch_bounds__(256) void k_agg(
    const int* __restrict__ offs, const int* __restrict__ ssrc,
    const ushort* __restrict__ h, const float* __restrict__ a_src,
    const float* __restrict__ a_dst, const float* __restrict__ x,
    const float* __restrict__ bias, const float* __restrict__ gamma,
    const float* __restrict__ beta, const float* __restrict__ prelu,
    float* __restrict__ out) {
  const int n = blockIdx.x * 4 + (threadIdx.x >> 6);
  const int l = threadIdx.x & 63;
  const int head = l >> 4;
  const float adv = a_dst[(n << 2) + head];
  const int beg = offs[n], end = offs[n + 1];
  const uint* hb = (const uint*)h;
  float acc0 = 0.f, acc1 = 0.f, ssum = 0.f;

  int i = beg;
  for (; i + 7 < end; i += 8) {
    const int s0 = ssrc[i + 0], s1 = ssrc[i + 1], s2 = ssrc[i + 2], s3 = ssrc[i + 3];
    const int s4 = ssrc[i + 4], s5 = ssrc[i + 5], s6 = ssrc[i + 6], s7 = ssrc[i + 7];
    const float e0 = a_src[(((uint)s0) << 2) + head];
    const float e1 = a_src[(((uint)s1) << 2) + head];
    const float e2 = a_src[(((uint)s2) << 2) + head];
    const float e3 = a_src[(((uint)s3) << 2) + head];
    const float e4 = a_src[(((uint)s4) << 2) + head];
    const float e5 = a_src[(((uint)s5) << 2) + head];
    const float e6 = a_src[(((uint)s6) << 2) + head];
    const float e7 = a_src[(((uint)s7) << 2) + head];
    const uint h0 = hb[(((uint)s0) << 6) + l];
    const uint h1 = hb[(((uint)s1) << 6) + l];
    const uint h2 = hb[(((uint)s2) << 6) + l];
    const uint h3 = hb[(((uint)s3) << 6) + l];
    const uint h4 = hb[(((uint)s4) << 6) + l];
    const uint h5 = hb[(((uint)s5) << 6) + l];
    const uint h6 = hb[(((uint)s6) << 6) + l];
    const uint h7 = hb[(((uint)s7) << 6) + l];
    float v0 = e0 + adv; v0 = fmaxf(v0, NEG_SLOPE * v0); const float p0 = __expf(v0);
    float v1 = e1 + adv; v1 = fmaxf(v1, NEG_SLOPE * v1); const float p1 = __expf(v1);
    float v2 = e2 + adv; v2 = fmaxf(v2, NEG_SLOPE * v2); const float p2 = __expf(v2);
    float v3 = e3 + adv; v3 = fmaxf(v3, NEG_SLOPE * v3); const float p3 = __expf(v3);
    float v4 = e4 + adv; v4 = fmaxf(v4, NEG_SLOPE * v4); const float p4 = __expf(v4);
    float v5 = e5 + adv; v5 = fmaxf(v5, NEG_SLOPE * v5); const float p5 = __expf(v5);
    float v6 = e6 + adv; v6 = fmaxf(v6, NEG_SLOPE * v6); const float p6 = __expf(v6);
    float v7 = e7 + adv; v7 = fmaxf(v7, NEG_SLOPE * v7); const float p7 = __expf(v7);
    ssum += ((p0 + p1) + (p2 + p3)) + ((p4 + p5) + (p6 + p7));
    acc0 += p0 * __uint_as_float(h0 << 16) + p1 * __uint_as_float(h1 << 16) +
            p2 * __uint_as_float(h2 << 16) + p3 * __uint_as_float(h3 << 16) +
            p4 * __uint_as_float(h4 << 16) + p5 * __uint_as_float(h5 << 16) +
            p6 * __uint_as_float(h6 << 16) + p7 * __uint_as_float(h7 << 16);
    acc1 += p0 * __uint_as_float(h0 & 0xffff0000u) + p1 * __uint_as_float(h1 & 0xffff0000u) +
            p2 * __uint_as_float(h2 & 0xffff0000u) + p3 * __uint_as_float(h3 & 0xffff0000u) +
            p4 * __uint_as_float(h4 & 0xffff0000u) + p5 * __uint_as_float(h5 & 0xffff0000u) +
            p6 * __uint_as_float(h6 & 0xffff0000u) + p7 * __uint_as_float(h7 & 0xffff0000u);
  }
  for (; i < end; ++i) {
    const int src = ssrc[i];
    float ev = a_src[(((uint)src) << 2) + head] + adv;
    ev = fmaxf(ev, NEG_SLOPE * ev);
    const float ex = __expf(ev);
    const uint hv = hb[(((uint)src) << 6) + l];
    ssum += ex;
    acc0 += ex * __uint_as_float(hv << 16);
    acc1 += ex * __uint_as_float(hv & 0xffff0000u);
  }

  float inv = 1.f / (ssum + 1e-16f);
  float v0 = acc0 * inv + bias[2 * l];
  float v1 = acc1 * inv + bias[2 * l + 1];
  float s1 = v0 + v1, s2 = v0 * v0 + v1 * v1;
  for (int off = 1; off < 64; off <<= 1) {
    s1 += __shfl_xor(s1, off);
    s2 += __shfl_xor(s2, off);
  }
  float mu = s1 * (1.f / DOUT);
  float var = s2 * (1.f / DOUT) - mu * mu;
  float rs = rsqrtf(var + LN_EPS);
  float pw = prelu[0];
  float2 xr = *(const float2*)&x[(size_t)n * DIN + 2 * l];
  float o0 = (v0 - mu) * rs * gamma[2 * l] + beta[2 * l];
  o0 = (o0 >= 0.f) ? o0 : pw * o0;
  float o1 = (v1 - mu) * rs * gamma[2 * l + 1] + beta[2 * l + 1];
  o1 = (o1 >= 0.f) ? o1 : pw * o1;
  *(float2*)&out[(size_t)n * DOUT + 2 * l] = make_float2(o0 + xr.x, o1 + xr.y);
}

// ---------------- launch ----------------
extern "C" void kernel_launch(void* const* d_in, const int* in_sizes, int n_in,
                              void* d_out, int out_size, void* d_ws, size_t ws_size,
                              hipStream_t stream) {
  const float* x       = (const float*)d_in[0];
  const int*   ei      = (const int*)d_in[1];
  const float* W       = (const float*)d_in[2];
  const float* att_src = (const float*)d_in[3];
  const float* att_dst = (const float*)d_in[4];
  const float* bias    = (const float*)d_in[5];
  const float* gamma   = (const float*)d_in[6];
  const float* beta    = (const float*)d_in[7];
  const float* prelu   = (const float*)d_in[8];
  float* out = (float*)d_out;

  char* ws = (char*)d_ws;
  size_t off = 0;
  auto alloc = [&](size_t bytes) -> void* {
    void* p = ws + off;
    off += (bytes + 255) & ~(size_t)255;
    return p;
  };
  ushort* h     = (ushort*)alloc((size_t)NNODES * DOUT * 2);
  ushort* Wt    = (ushort*)alloc((size_t)DIN * DOUT * 2);
  float* a_src  = (float*)alloc((size_t)NNODES * NHEADS * 4);
  float* a_dst  = (float*)alloc((size_t)NNODES * NHEADS * 4);
  int*   deg    = (int*)alloc((size_t)NNODES * 4);
  int*   offs   = (int*)alloc((size_t)(NNODES + 1) * 4);
  int*   rank   = (int*)alloc((size_t)NEDGES * 4);
  int*   ssrc   = (int*)alloc((size_t)NEDGES * 4);
  const int NB = (NNODES + 255) / 256;  // 391
  int*   bsum   = (int*)alloc((size_t)NB * 4);

  hipMemsetAsync(deg, 0, (size_t)NNODES * 4, stream);
  k_hist_wt<<<NBH + 1, 256, 0, stream>>>(ei, deg, rank, W, Wt);
  k_gemm<<<(NNODES + BM - 1) / BM, 256, 0, stream>>>(x, Wt, att_src, att_dst, h,
                                                     a_src, a_dst);
  k_blocksum<<<NB, 256, 0, stream>>>(deg, bsum);
  k_scanbsum<<<1, 512, 0, stream>>>(bsum, NB, offs);
  k_offsets<<<NB, 256, 0, stream>>>(deg, bsum, offs);
  k_scatter<<<NBH, 256, 0, stream>>>(ei, rank, offs, ssrc);
  k_agg<<<NNODES / 4, 256, 0, stream>>>(offs, ssrc, h, a_src, a_dst, x, bias, gamma,
                                        beta, prelu, out);
}